// Round 8
// baseline (1994.047 us; speedup 1.0000x reference)
//
#include <hip/hip_runtime.h>
#include <math.h>

#define T_SEQ 1024
#define LH 125      // lstm hidden
#define G4 500      // 4*L gates

typedef unsigned int v8u __attribute__((ext_vector_type(8)));
typedef _Float16 f16x2 __attribute__((ext_vector_type(2)));

__device__ __forceinline__ float ftanh(float x) {
    float e = __builtin_amdgcn_exp2f(x * -2.8853900817779268f);
    return 2.f * __builtin_amdgcn_rcpf(1.f + e) - 1.f;
}

// DPP quad-perm moves: xor1=[1,0,3,2]=0xB1, xor2=[2,3,0,1]=0x4E, xor3=[3,2,1,0]=0x1B
__device__ __forceinline__ float dpp_xor1(float x) {
    int xi = __float_as_int(x);
    return __int_as_float(__builtin_amdgcn_update_dpp(xi, xi, 0xB1, 0xF, 0xF, true));
}
__device__ __forceinline__ float dpp_xor2(float x) {
    int xi = __float_as_int(x);
    return __int_as_float(__builtin_amdgcn_update_dpp(xi, xi, 0x4E, 0xF, 0xF, true));
}
__device__ __forceinline__ float dpp_xor3(float x) {
    int xi = __float_as_int(x);
    return __int_as_float(__builtin_amdgcn_update_dpp(xi, xi, 0x1B, 0xF, 0xF, true));
}

__device__ __forceinline__ f16x2 as_h2(unsigned int u) {
    return __builtin_bit_cast(f16x2, u);
}

// 16-term f16 dot: 8x v_dot2_f32_f16, operands are compile-time dword extracts
__device__ __forceinline__ float dot8(v8u w, v8u h, float acc) {
#define D8(p) acc = __builtin_amdgcn_fdot2(as_h2(w[p]), as_h2(h[p]), acc, false);
    D8(0) D8(1) D8(2) D8(3) D8(4) D8(5) D8(6) D8(7)
#undef D8
    return acc;
}

// pack 16 f32 weights (with validity mask) into 8 dwords of f16 pairs
__device__ __forceinline__ v8u packw8(const float* __restrict__ wp, int nvalid) {
    v8u r;
#define PW(d) { \
    float a = (2*(d)   < nvalid) ? wp[2*(d)]   : 0.f; \
    float b = (2*(d)+1 < nvalid) ? wp[2*(d)+1] : 0.f; \
    f16x2 t; t[0] = (_Float16)a; t[1] = (_Float16)b; \
    r[d] = __builtin_bit_cast(unsigned int, t); }
    PW(0) PW(1) PW(2) PW(3) PW(4) PW(5) PW(6) PW(7)
#undef PW
    return r;
}

// ---------------- layer-0 input projection, embedding fused, 4 timesteps/block
// Stores pre in interleaved layout: pre[t][unit][gate] (gate: 0=i,1=f,2=g,3=o)
__global__ void k_preproj0(const int* __restrict__ wid, const int* __restrict__ pid,
                           const float* __restrict__ W_emb, const float* __restrict__ P_emb,
                           const float* __restrict__ Wf, const float* __restrict__ bf,
                           const float* __restrict__ Wb, const float* __restrict__ bb,
                           float* __restrict__ pf, float* __restrict__ pb) {
    __shared__ float xs[4][128];
    const int t0 = blockIdx.x * 4;
    const int tid = threadIdx.x;   // 512
    for (int tt = 0; tt < 4; ++tt) {
        int t = t0 + tt;
        for (int k = tid; k < 125; k += 512)
            xs[tt][k] = (k < 100) ? W_emb[wid[t] * 100 + k] : P_emb[pid[t] * 25 + (k - 100)];
    }
    __syncthreads();
    const int j = tid;
    if (j < G4) {
        const float* wf = Wf + j * 125;
        const float* wb = Wb + j * 125;
        float af0 = bf[j], af1 = af0, af2 = af0, af3 = af0;
        float ab0 = bb[j], ab1 = ab0, ab2 = ab0, ab3 = ab0;
        #pragma unroll 5
        for (int k = 0; k < 125; ++k) {
            float wfk = wf[k], wbk = wb[k];
            af0 += wfk * xs[0][k]; af1 += wfk * xs[1][k];
            af2 += wfk * xs[2][k]; af3 += wfk * xs[3][k];
            ab0 += wbk * xs[0][k]; ab1 += wbk * xs[1][k];
            ab2 += wbk * xs[2][k]; ab3 += wbk * xs[3][k];
        }
        int g = j / 125, u = j - g * 125;
        int off = u * 4 + g;
        pf[(t0 + 0) * G4 + off] = af0; pf[(t0 + 1) * G4 + off] = af1;
        pf[(t0 + 2) * G4 + off] = af2; pf[(t0 + 3) * G4 + off] = af3;
        pb[(t0 + 0) * G4 + off] = ab0; pb[(t0 + 1) * G4 + off] = ab1;
        pb[(t0 + 2) * G4 + off] = ab2; pb[(t0 + 3) * G4 + off] = ab3;
    }
}

// ---------------- layer-1 input projection (input = h1, K=250), interleaved store
__global__ void k_preproj1(const float* __restrict__ h1,
                           const float* __restrict__ Wf, const float* __restrict__ bf,
                           const float* __restrict__ Wb, const float* __restrict__ bb,
                           float* __restrict__ pf, float* __restrict__ pb) {
    __shared__ float xs[4][256];
    const int t0 = blockIdx.x * 4;
    const int tid = threadIdx.x;   // 512
    for (int tt = 0; tt < 4; ++tt) {
        int t = t0 + tt;
        for (int k = tid; k < 250; k += 512) xs[tt][k] = h1[t * 250 + k];
    }
    __syncthreads();
    const int j = tid;
    if (j < G4) {
        const float* wf = Wf + j * 250;
        const float* wb = Wb + j * 250;
        float af0 = bf[j], af1 = af0, af2 = af0, af3 = af0;
        float ab0 = bb[j], ab1 = ab0, ab2 = ab0, ab3 = ab0;
        #pragma unroll 5
        for (int k = 0; k < 250; ++k) {
            float wfk = wf[k], wbk = wb[k];
            af0 += wfk * xs[0][k]; af1 += wfk * xs[1][k];
            af2 += wfk * xs[2][k]; af3 += wfk * xs[3][k];
            ab0 += wbk * xs[0][k]; ab1 += wbk * xs[1][k];
            ab2 += wbk * xs[2][k]; ab3 += wbk * xs[3][k];
        }
        int g = j / 125, u = j - g * 125;
        int off = u * 4 + g;
        pf[(t0 + 0) * G4 + off] = af0; pf[(t0 + 1) * G4 + off] = af1;
        pf[(t0 + 2) * G4 + off] = af2; pf[(t0 + 3) * G4 + off] = af3;
        pb[(t0 + 0) * G4 + off] = ab0; pb[(t0 + 1) * G4 + off] = ab1;
        pb[(t0 + 2) * G4 + off] = ab2; pb[(t0 + 3) * G4 + off] = ab3;
    }
}

// ---------------- sequential LSTM scan: BOTH directions in ONE 1024-thread block.
// Waves 0-7 = forward, waves 8-15 = backward -> each SIMD hosts 2 fwd + 2 bwd waves;
// when one direction's waves sit in their serial tail (LDS latency, DPP reduce,
// exp2/rcp chains), the other direction's waves issue dots -> latency overlapped.
// Within a direction: jg = t9>>2 owns hidden unit jg; kp = t9&3 owns k-slice and gate kp.
__global__ void __attribute__((amdgpu_flat_work_group_size(1024, 1024)))
__attribute__((amdgpu_waves_per_eu(4, 4)))
k_scan(const float* __restrict__ pf, const float* __restrict__ Wf,
       const float* __restrict__ pb, const float* __restrict__ Wb,
       float* __restrict__ hout) {
    const int tid = threadIdx.x;
    const int dir = tid >> 9;                 // wave-uniform
    const int t9  = tid & 511;
    const float* __restrict__ pre = dir ? pb : pf;   // [T][125][4]
    const float* __restrict__ Whh = dir ? Wb : Wf;
    const int col0 = dir ? 0 : 125;

    // per-dir: 2 buf x 4 regions x (32 used + 16 pad) halves
    __shared__ __align__(32) _Float16 h_lds[2 * 2 * 4 * 48];

    const int kp  = t9 & 3;
    const int jg  = t9 >> 2;       // 0..127
    const int kbase = kp * 32;
    const bool vj = (jg < LH);
    const int u = vj ? jg : (LH - 1);

    const bool b0 = (kp & 1) != 0;
    const bool b1 = (kp & 2) != 0;
    const bool lowpair = (kp < 2);

    // valid k counts for the two 16-wide sub-slices
    int nv0 = LH - kbase;       nv0 = nv0 < 0 ? 0 : (nv0 > 16 ? 16 : nv0);
    int nv1 = LH - kbase - 16;  nv1 = nv1 < 0 ? 0 : (nv1 > 16 ? 16 : nv1);
    if (!vj) { nv0 = 0; nv1 = 0; }

    // weights: 4 gate rows x 32 k, f16 pairs in uint dwords (register-resident)
#define LWG(lo, hi, row0) v8u lo, hi; { \
        const float* wp = Whh + (row0 + u) * LH + kbase; \
        lo = packw8(wp, nv0); hi = packw8(wp + 16, nv1); }
    LWG(wi_lo, wi_hi, 0) LWG(wf_lo, wf_hi, 125) LWG(wg_lo, wg_hi, 250) LWG(wo_lo, wo_hi, 375)
#undef LWG

    // own-gate nonlinearity constants: sigmoid for kp in {0,1,3}, tanh for kp==2
    const bool is_sig = (kp != 2);
    const float Ac  = is_sig ? 1.f : 2.f;
    const float Bc2 = is_sig ? -1.4426950408889634f : -2.8853900817779268f; // B/ln2
    const float Cc  = is_sig ? 0.f : -1.f;

    for (int q = tid; q < 2 * 2 * 4 * 48; q += 1024) h_lds[q] = (_Float16)0.f;
    float c = 0.f;
    __syncthreads();

    const bool writes_h = vj && (kp == (jg >> 5));
    const bool writes_g = vj && (kp == 0);

    // int-offset walking pointers; one-row-over prefetch stays inside workspace
    const int pstride = dir ? -G4 : G4;
    int poff = (dir ? (T_SEQ - 1) * G4 : 0) + u * 4 + kp;
    const int gstride = dir ? -250 : 250;
    int goff = (dir ? (T_SEQ - 1) * 250 : 0) + col0 + jg;
    float pv = pre[poff];
    poff += pstride;

    const _Float16* hbase = &h_lds[dir * 384 + kp * 48];
    _Float16* hwr = &h_lds[dir * 384 + kp * 48 + (jg & 31)];

#define SCAN_STEP(CUR, NXT) { \
    float pvn = pre[poff]; poff += pstride; \
    const _Float16* hp = hbase + (CUR) * 192; \
    v8u hlo = *reinterpret_cast<const v8u*>(hp); \
    v8u hhi = *reinterpret_cast<const v8u*>(hp + 16); \
    float ai = dot8(wi_hi, hhi, dot8(wi_lo, hlo, 0.f)); \
    float af = dot8(wf_hi, hhi, dot8(wf_lo, hlo, 0.f)); \
    float ag = dot8(wg_hi, hhi, dot8(wg_lo, hlo, 0.f)); \
    float ao = dot8(wo_hi, hhi, dot8(wo_lo, hlo, 0.f)); \
    float uL = lowpair ? ai : ag; \
    float vL = lowpair ? ag : ai; \
    float A2 = uL + dpp_xor2(vL); \
    float wL = lowpair ? af : ao; \
    float xL = lowpair ? ao : af; \
    float B2 = wL + dpp_xor2(xL); \
    float snd = b0 ? A2 : B2; \
    float own = b0 ? B2 : A2; \
    float gsum = own + dpp_xor1(snd); \
    float gv = Ac * __builtin_amdgcn_rcpf( \
                   1.f + __builtin_amdgcn_exp2f(Bc2 * (gsum + pv))) + Cc; \
    float r1 = dpp_xor1(gv); \
    float r2 = dpp_xor2(gv); \
    float r3 = dpp_xor3(gv); \
    float m   = (b0 ? r1 : gv) * (b0 ? r3 : r2); \
    float s01 = b0 ? gv : r1; \
    float s23 = b0 ? r2 : r3; \
    float gfv = b1 ? s23 : s01; \
    float gov = b1 ? s01 : s23; \
    c = gfv * c + m; \
    float hnew = gov * ftanh(c); \
    if (writes_h) hwr[(NXT) * 192] = (_Float16)hnew; \
    if (writes_g) hout[goff] = hnew; \
    goff += gstride; \
    __syncthreads(); \
    pv = pvn; \
}

    for (int s2 = 0; s2 < T_SEQ; s2 += 2) {
        SCAN_STEP(0, 1)
        SCAN_STEP(1, 0)
    }
#undef SCAN_STEP
}

// ---------------- head' = h2 @ FOH + bias ; mod = h2 @ FOM
__global__ void k_headmod(const float* __restrict__ h2,
                          const float* __restrict__ FOH, const float* __restrict__ FOM,
                          const float* __restrict__ bias,
                          float* __restrict__ headp, float* __restrict__ modv) {
    __shared__ float hs[250];
    int t = blockIdx.x, tid = threadIdx.x;   // block 256
    for (int k = tid; k < 250; k += 256) hs[k] = h2[t * 250 + k];
    __syncthreads();
    if (tid < 100) {
        float a = 0.f;
        #pragma unroll 5
        for (int k = 0; k < 250; ++k) a += hs[k] * FOH[k * 100 + tid];
        headp[t * 100 + tid] = a + bias[tid];
    } else if (tid >= 128 && tid < 228) {
        int h = tid - 128;
        float a = 0.f;
        #pragma unroll 5
        for (int k = 0; k < 250; ++k) a += hs[k] * FOM[k * 100 + h];
        modv[t * 100 + h] = a;
    }
}

// ---------------- scores[i][j] = sum_h tanh(head'[i][h] + mod[j][h]) * outW[h]
__global__ void k_score(const float* __restrict__ headp, const float* __restrict__ modv,
                        const float* __restrict__ outw, float* __restrict__ out) {
    __shared__ float hh[16][100];
    __shared__ float mm[16][100];
    __shared__ float ow[100];
    const int bi = blockIdx.y, bj = blockIdx.x;
    const int tx = threadIdx.x, ty = threadIdx.y;   // 16x16
    const int tid = ty * 16 + tx;
    for (int q = tid; q < 1600; q += 256) {
        int r = q / 100, cidx = q % 100;
        hh[r][cidx] = headp[(bi * 16 + r) * 100 + cidx];
        mm[r][cidx] = modv[(bj * 16 + r) * 100 + cidx];
    }
    if (tid < 100) ow[tid] = outw[tid];
    __syncthreads();
    float acc = 0.f;
    #pragma unroll 4
    for (int h = 0; h < 100; ++h) {
        float e = __builtin_amdgcn_exp2f((hh[ty][h] + mm[tx][h]) * -2.8853900817779268f);
        acc += (2.f * __builtin_amdgcn_rcpf(1.f + e) - 1.f) * ow[h];
    }
    out[(bi * 16 + ty) * 1024 + (bj * 16 + tx)] = acc;
}

extern "C" void kernel_launch(void* const* d_in, const int* in_sizes, int n_in,
                              void* d_out, int out_size, void* d_ws, size_t ws_size,
                              hipStream_t stream) {
    const int*   wid    = (const int*)d_in[0];
    const int*   pid    = (const int*)d_in[1];
    const float* W_emb  = (const float*)d_in[2];
    const float* P_emb  = (const float*)d_in[3];
    const float* Wih_f0 = (const float*)d_in[4];
    const float* Whh_f0 = (const float*)d_in[5];
    const float* b_f0   = (const float*)d_in[6];
    const float* Wih_b0 = (const float*)d_in[7];
    const float* Whh_b0 = (const float*)d_in[8];
    const float* b_b0   = (const float*)d_in[9];
    const float* Wih_f1 = (const float*)d_in[10];
    const float* Whh_f1 = (const float*)d_in[11];
    const float* b_f1   = (const float*)d_in[12];
    const float* Wih_b1 = (const float*)d_in[13];
    const float* Whh_b1 = (const float*)d_in[14];
    const float* b_b1   = (const float*)d_in[15];
    const float* FOH    = (const float*)d_in[16];
    const float* FOM    = (const float*)d_in[17];
    const float* hidB   = (const float*)d_in[18];
    const float* outW   = (const float*)d_in[19];
    float* out = (float*)d_out;
    float* ws  = (float*)d_ws;

    float* pf    = ws;                  // 1024*500 (interleaved [t][u][gate])
    float* pb    = pf    + 512000;
    float* h1    = pb    + 512000;      // 1024*250
    float* h2    = h1    + 256000;
    float* headp = h2    + 256000;      // 1024*100
    float* modv  = headp + 102400;

    k_preproj0<<<256, 512, 0, stream>>>(wid, pid, W_emb, P_emb,
                                        Wih_f0, b_f0, Wih_b0, b_b0, pf, pb);
    k_scan<<<1, 1024, 0, stream>>>(pf, Whh_f0, pb, Whh_b0, h1);

    k_preproj1<<<256, 512, 0, stream>>>(h1, Wih_f1, b_f1, Wih_b1, b_b1, pf, pb);
    k_scan<<<1, 1024, 0, stream>>>(pf, Whh_f1, pb, Whh_b1, h2);

    k_headmod<<<T_SEQ, 256, 0, stream>>>(h2, FOH, FOM, hidB, headp, modv);
    dim3 gs(64, 64), bs(16, 16);
    k_score<<<gs, bs, 0, stream>>>(headp, modv, outW, out);
}

// Round 9
// 1012.141 us; speedup vs baseline: 1.9701x; 1.9701x over previous
//
#include <hip/hip_runtime.h>
#include <math.h>

#define T_SEQ 1024
#define LH 125      // lstm hidden
#define G4 500      // 4*L gates

typedef _Float16 v8h __attribute__((ext_vector_type(8)));
typedef float f32x4 __attribute__((ext_vector_type(4)));

__device__ __forceinline__ float fsig(float x) {
    return __builtin_amdgcn_rcpf(1.f + __builtin_amdgcn_exp2f(x * -1.4426950408889634f));
}
__device__ __forceinline__ float ftanh(float x) {
    float e = __builtin_amdgcn_exp2f(x * -2.8853900817779268f);
    return 2.f * __builtin_amdgcn_rcpf(1.f + e) - 1.f;
}

// pack 8 f32 weights -> 8 f16 (zero for k >= LH), compile-time element indices
__device__ __forceinline__ v8h packa8(const float* __restrict__ rowp, int kbase) {
    v8h r;
#define PA(j) { int k = kbase + (j); r[j] = (k < LH) ? (_Float16)rowp[k] : (_Float16)0.f; }
    PA(0) PA(1) PA(2) PA(3) PA(4) PA(5) PA(6) PA(7)
#undef PA
    return r;
}

// ---------------- layer-0 input projection, embedding fused, 4 timesteps/block
// Stores pre interleaved: pre[t][unit][gate] (gate: 0=i,1=f,2=g,3=o)
__global__ void k_preproj0(const int* __restrict__ wid, const int* __restrict__ pid,
                           const float* __restrict__ W_emb, const float* __restrict__ P_emb,
                           const float* __restrict__ Wf, const float* __restrict__ bf,
                           const float* __restrict__ Wb, const float* __restrict__ bb,
                           float* __restrict__ pf, float* __restrict__ pb) {
    __shared__ float xs[4][128];
    const int t0 = blockIdx.x * 4;
    const int tid = threadIdx.x;   // 512
    for (int tt = 0; tt < 4; ++tt) {
        int t = t0 + tt;
        for (int k = tid; k < 125; k += 512)
            xs[tt][k] = (k < 100) ? W_emb[wid[t] * 100 + k] : P_emb[pid[t] * 25 + (k - 100)];
    }
    __syncthreads();
    const int j = tid;
    if (j < G4) {
        const float* wf = Wf + j * 125;
        const float* wb = Wb + j * 125;
        float af0 = bf[j], af1 = af0, af2 = af0, af3 = af0;
        float ab0 = bb[j], ab1 = ab0, ab2 = ab0, ab3 = ab0;
        #pragma unroll 5
        for (int k = 0; k < 125; ++k) {
            float wfk = wf[k], wbk = wb[k];
            af0 += wfk * xs[0][k]; af1 += wfk * xs[1][k];
            af2 += wfk * xs[2][k]; af3 += wfk * xs[3][k];
            ab0 += wbk * xs[0][k]; ab1 += wbk * xs[1][k];
            ab2 += wbk * xs[2][k]; ab3 += wbk * xs[3][k];
        }
        int g = j / 125, u = j - g * 125;
        int off = u * 4 + g;
        pf[(t0 + 0) * G4 + off] = af0; pf[(t0 + 1) * G4 + off] = af1;
        pf[(t0 + 2) * G4 + off] = af2; pf[(t0 + 3) * G4 + off] = af3;
        pb[(t0 + 0) * G4 + off] = ab0; pb[(t0 + 1) * G4 + off] = ab1;
        pb[(t0 + 2) * G4 + off] = ab2; pb[(t0 + 3) * G4 + off] = ab3;
    }
}

// ---------------- layer-1 input projection (input = h1, K=250), interleaved store
__global__ void k_preproj1(const float* __restrict__ h1,
                           const float* __restrict__ Wf, const float* __restrict__ bf,
                           const float* __restrict__ Wb, const float* __restrict__ bb,
                           float* __restrict__ pf, float* __restrict__ pb) {
    __shared__ float xs[4][256];
    const int t0 = blockIdx.x * 4;
    const int tid = threadIdx.x;   // 512
    for (int tt = 0; tt < 4; ++tt) {
        int t = t0 + tt;
        for (int k = tid; k < 250; k += 512) xs[tt][k] = h1[t * 250 + k];
    }
    __syncthreads();
    const int j = tid;
    if (j < G4) {
        const float* wf = Wf + j * 250;
        const float* wb = Wb + j * 250;
        float af0 = bf[j], af1 = af0, af2 = af0, af3 = af0;
        float ab0 = bb[j], ab1 = ab0, ab2 = ab0, ab3 = ab0;
        #pragma unroll 5
        for (int k = 0; k < 250; ++k) {
            float wfk = wf[k], wbk = wb[k];
            af0 += wfk * xs[0][k]; af1 += wfk * xs[1][k];
            af2 += wfk * xs[2][k]; af3 += wfk * xs[3][k];
            ab0 += wbk * xs[0][k]; ab1 += wbk * xs[1][k];
            ab2 += wbk * xs[2][k]; ab3 += wbk * xs[3][k];
        }
        int g = j / 125, u = j - g * 125;
        int off = u * 4 + g;
        pf[(t0 + 0) * G4 + off] = af0; pf[(t0 + 1) * G4 + off] = af1;
        pf[(t0 + 2) * G4 + off] = af2; pf[(t0 + 3) * G4 + off] = af3;
        pb[(t0 + 0) * G4 + off] = ab0; pb[(t0 + 1) * G4 + off] = ab1;
        pb[(t0 + 2) * G4 + off] = ab2; pb[(t0 + 3) * G4 + off] = ab3;
    }
}

// ---------------- MFMA LSTM scan, one 512-thread block (8 waves) per direction.
// Whh rows used in interleaved order row' = 4*unit + gate. Wave w owns rows'
// [64w, 64w+64) = units [16w, 16w+16). Per wave: 4 M-tiles (16 rows') x 4 K-tiles
// (32 k) of mfma_f32_16x16x32_f16. B = h broadcast to all 16 cols (every lane
// reads the same k-slice per 16-lane group) -> D cols all equal. C layout
// (HW-verified): row'-in-tile = (lane>>4)*4 + reg -> each lane's 4 acc regs are
// one unit's {i,f,g,o}. m-tile selected per-lane via cndmask (m = lane&3) ->
// lane owns unit 16w + 4*(lane&3) + (lane>>4), 4x replicated (lane bits 2,3).
// Entire LSTM tail is in-lane: no cross-lane reduce at all. One barrier/step.
__global__ void __attribute__((amdgpu_flat_work_group_size(512, 512)))
__attribute__((amdgpu_waves_per_eu(2, 2)))
k_scan(const float* __restrict__ pf, const float* __restrict__ Wf,
       const float* __restrict__ pb, const float* __restrict__ Wb,
       float* __restrict__ hout) {
    const int dir = blockIdx.x;
    const float* __restrict__ pre = dir ? pb : pf;   // [T][125][4]
    const float* __restrict__ Whh = dir ? Wb : Wf;   // [4][125][125] original
    const int col0 = dir ? 0 : 125;

    __shared__ __align__(32) _Float16 h_lds[2 * 128];   // 2 buffers x 128 halves (125 + pad=0)

    const int t9   = threadIdx.x;
    const int w    = t9 >> 6;        // wave 0..7
    const int lane = t9 & 63;
    const int lane15 = lane & 15;
    const int hi16   = lane >> 4;    // 0..3
    const bool mb0 = (lane & 1) != 0;
    const bool mb1 = (lane & 2) != 0;

    const int uo    = 4 * (lane & 3) + hi16;   // unit-in-wave this lane owns
    const int u_raw = 16 * w + uo;
    const bool valid = (u_raw < LH);
    const int u = valid ? u_raw : (LH - 1);
    const bool writer = ((lane & 12) == 0) && valid;

    // ---- A fragments: 4 M-tiles x 4 K-tiles, row' = 64w + 16m + lane15 (clamped),
    // orig row = (row'&3)*125 + (row'>>2); k = kt*32 + hi16*8 + j.
#define LROW(m) int ro##m; { int rp = 64 * w + 16 * m + lane15; if (rp > 499) rp = 499; \
                             ro##m = (rp & 3) * 125 + (rp >> 2); }
    LROW(0) LROW(1) LROW(2) LROW(3)
#undef LROW
#define LA(m) v8h a##m##0 = packa8(Whh + ro##m * LH, hi16 * 8); \
              v8h a##m##1 = packa8(Whh + ro##m * LH, 32 + hi16 * 8); \
              v8h a##m##2 = packa8(Whh + ro##m * LH, 64 + hi16 * 8); \
              v8h a##m##3 = packa8(Whh + ro##m * LH, 96 + hi16 * 8);
    LA(0) LA(1) LA(2) LA(3)
#undef LA

    for (int q = t9; q < 2 * 128; q += 512) h_lds[q] = (_Float16)0.f;
    float c = 0.f;
    __syncthreads();

    // walking int offsets (one-over prefetch stays inside workspace: pf/pb adjacent)
    const int pstride = dir ? -G4 : G4;
    int poff = (dir ? (T_SEQ - 1) * G4 : 0) + u * 4;
    const int gstride = dir ? -250 : 250;
    int goff = (dir ? (T_SEQ - 1) * 250 : 0) + col0 + u;
    float4 pv4 = *reinterpret_cast<const float4*>(pre + poff);
    poff += pstride;

    const int bbase = hi16 * 8;   // halves offset within a K-tile row

#define SCAN_STEP(CUR, NXT) { \
    float4 pvn = *reinterpret_cast<const float4*>(pre + poff); poff += pstride; \
    const _Float16* hb = &h_lds[(CUR) * 128 + bbase]; \
    v8h bb0 = *reinterpret_cast<const v8h*>(hb); \
    v8h bb1 = *reinterpret_cast<const v8h*>(hb + 32); \
    v8h bb2 = *reinterpret_cast<const v8h*>(hb + 64); \
    v8h bb3 = *reinterpret_cast<const v8h*>(hb + 96); \
    f32x4 z = {0.f, 0.f, 0.f, 0.f}; \
    f32x4 acc0 = __builtin_amdgcn_mfma_f32_16x16x32_f16(a00, bb0, z, 0, 0, 0); \
    acc0 = __builtin_amdgcn_mfma_f32_16x16x32_f16(a01, bb1, acc0, 0, 0, 0); \
    acc0 = __builtin_amdgcn_mfma_f32_16x16x32_f16(a02, bb2, acc0, 0, 0, 0); \
    acc0 = __builtin_amdgcn_mfma_f32_16x16x32_f16(a03, bb3, acc0, 0, 0, 0); \
    f32x4 acc1 = __builtin_amdgcn_mfma_f32_16x16x32_f16(a10, bb0, z, 0, 0, 0); \
    acc1 = __builtin_amdgcn_mfma_f32_16x16x32_f16(a11, bb1, acc1, 0, 0, 0); \
    acc1 = __builtin_amdgcn_mfma_f32_16x16x32_f16(a12, bb2, acc1, 0, 0, 0); \
    acc1 = __builtin_amdgcn_mfma_f32_16x16x32_f16(a13, bb3, acc1, 0, 0, 0); \
    f32x4 acc2 = __builtin_amdgcn_mfma_f32_16x16x32_f16(a20, bb0, z, 0, 0, 0); \
    acc2 = __builtin_amdgcn_mfma_f32_16x16x32_f16(a21, bb1, acc2, 0, 0, 0); \
    acc2 = __builtin_amdgcn_mfma_f32_16x16x32_f16(a22, bb2, acc2, 0, 0, 0); \
    acc2 = __builtin_amdgcn_mfma_f32_16x16x32_f16(a23, bb3, acc2, 0, 0, 0); \
    f32x4 acc3 = __builtin_amdgcn_mfma_f32_16x16x32_f16(a30, bb0, z, 0, 0, 0); \
    acc3 = __builtin_amdgcn_mfma_f32_16x16x32_f16(a31, bb1, acc3, 0, 0, 0); \
    acc3 = __builtin_amdgcn_mfma_f32_16x16x32_f16(a32, bb2, acc3, 0, 0, 0); \
    acc3 = __builtin_amdgcn_mfma_f32_16x16x32_f16(a33, bb3, acc3, 0, 0, 0); \
    float x01_0 = mb0 ? acc1[0] : acc0[0]; float x23_0 = mb0 ? acc3[0] : acc2[0]; \
    float x01_1 = mb0 ? acc1[1] : acc0[1]; float x23_1 = mb0 ? acc3[1] : acc2[1]; \
    float x01_2 = mb0 ? acc1[2] : acc0[2]; float x23_2 = mb0 ? acc3[2] : acc2[2]; \
    float x01_3 = mb0 ? acc1[3] : acc0[3]; float x23_3 = mb0 ? acc3[3] : acc2[3]; \
    float fr0 = mb1 ? x23_0 : x01_0; \
    float fr1 = mb1 ? x23_1 : x01_1; \
    float fr2 = mb1 ? x23_2 : x01_2; \
    float fr3 = mb1 ? x23_3 : x01_3; \
    float gi = fsig(fr0 + pv4.x); \
    float gf = fsig(fr1 + pv4.y); \
    float gg = ftanh(fr2 + pv4.z); \
    float go = fsig(fr3 + pv4.w); \
    c = gf * c + gi * gg; \
    float hnew = go * ftanh(c); \
    if (writer) { \
        h_lds[(NXT) * 128 + u] = (_Float16)hnew; \
        hout[goff] = hnew; \
    } \
    goff += gstride; \
    __syncthreads(); \
    pv4 = pvn; \
}

    for (int s2 = 0; s2 < T_SEQ; s2 += 2) {
        SCAN_STEP(0, 1)
        SCAN_STEP(1, 0)
    }
#undef SCAN_STEP
}

// ---------------- head' = h2 @ FOH + bias ; mod = h2 @ FOM
__global__ void k_headmod(const float* __restrict__ h2,
                          const float* __restrict__ FOH, const float* __restrict__ FOM,
                          const float* __restrict__ bias,
                          float* __restrict__ headp, float* __restrict__ modv) {
    __shared__ float hs[250];
    int t = blockIdx.x, tid = threadIdx.x;   // block 256
    for (int k = tid; k < 250; k += 256) hs[k] = h2[t * 250 + k];
    __syncthreads();
    if (tid < 100) {
        float a = 0.f;
        #pragma unroll 5
        for (int k = 0; k < 250; ++k) a += hs[k] * FOH[k * 100 + tid];
        headp[t * 100 + tid] = a + bias[tid];
    } else if (tid >= 128 && tid < 228) {
        int h = tid - 128;
        float a = 0.f;
        #pragma unroll 5
        for (int k = 0; k < 250; ++k) a += hs[k] * FOM[k * 100 + h];
        modv[t * 100 + h] = a;
    }
}

// ---------------- scores[i][j] = sum_h tanh(head'[i][h] + mod[j][h]) * outW[h]
__global__ void k_score(const float* __restrict__ headp, const float* __restrict__ modv,
                        const float* __restrict__ outw, float* __restrict__ out) {
    __shared__ float hh[16][100];
    __shared__ float mm[16][100];
    __shared__ float ow[100];
    const int bi = blockIdx.y, bj = blockIdx.x;
    const int tx = threadIdx.x, ty = threadIdx.y;   // 16x16
    const int tid = ty * 16 + tx;
    for (int q = tid; q < 1600; q += 256) {
        int r = q / 100, cidx = q % 100;
        hh[r][cidx] = headp[(bi * 16 + r) * 100 + cidx];
        mm[r][cidx] = modv[(bj * 16 + r) * 100 + cidx];
    }
    if (tid < 100) ow[tid] = outw[tid];
    __syncthreads();
    float acc = 0.f;
    #pragma unroll 4
    for (int h = 0; h < 100; ++h) {
        float e = __builtin_amdgcn_exp2f((hh[ty][h] + mm[tx][h]) * -2.8853900817779268f);
        acc += (2.f * __builtin_amdgcn_rcpf(1.f + e) - 1.f) * ow[h];
    }
    out[(bi * 16 + ty) * 1024 + (bj * 16 + tx)] = acc;
}

extern "C" void kernel_launch(void* const* d_in, const int* in_sizes, int n_in,
                              void* d_out, int out_size, void* d_ws, size_t ws_size,
                              hipStream_t stream) {
    const int*   wid    = (const int*)d_in[0];
    const int*   pid    = (const int*)d_in[1];
    const float* W_emb  = (const float*)d_in[2];
    const float* P_emb  = (const float*)d_in[3];
    const float* Wih_f0 = (const float*)d_in[4];
    const float* Whh_f0 = (const float*)d_in[5];
    const float* b_f0   = (const float*)d_in[6];
    const float* Wih_b0 = (const float*)d_in[7];
    const float* Whh_b0 = (const float*)d_in[8];
    const float* b_b0   = (const float*)d_in[9];
    const float* Wih_f1 = (const float*)d_in[10];
    const float* Whh_f1 = (const float*)d_in[11];
    const float* b_f1   = (const float*)d_in[12];
    const float* Wih_b1 = (const float*)d_in[13];
    const float* Whh_b1 = (const float*)d_in[14];
    const float* b_b1   = (const float*)d_in[15];
    const float* FOH    = (const float*)d_in[16];
    const float* FOM    = (const float*)d_in[17];
    const float* hidB   = (const float*)d_in[18];
    const float* outW   = (const float*)d_in[19];
    float* out = (float*)d_out;
    float* ws  = (float*)d_ws;

    float* pf    = ws;                  // 1024*500 (interleaved [t][u][gate])
    float* pb    = pf    + 512000;
    float* h1    = pb    + 512000;      // 1024*250
    float* h2    = h1    + 256000;
    float* headp = h2    + 256000;      // 1024*100
    float* modv  = headp + 102400;

    k_preproj0<<<256, 512, 0, stream>>>(wid, pid, W_emb, P_emb,
                                        Wih_f0, b_f0, Wih_b0, b_b0, pf, pb);
    k_scan<<<2, 512, 0, stream>>>(pf, Whh_f0, pb, Whh_b0, h1);

    k_preproj1<<<256, 512, 0, stream>>>(h1, Wih_f1, b_f1, Wih_b1, b_b1, pf, pb);
    k_scan<<<2, 512, 0, stream>>>(pf, Whh_f1, pb, Whh_b1, h2);

    k_headmod<<<T_SEQ, 256, 0, stream>>>(h2, FOH, FOM, hidB, headp, modv);
    dim3 gs(64, 64), bs(16, 16);
    k_score<<<gs, bs, 0, stream>>>(headp, modv, outW, out);
}